// Round 3
// baseline (212.486 us; speedup 1.0000x reference)
//
#include <hip/hip_runtime.h>
#include <hip/hip_bf16.h>
#include <cstdint>
#include <cstddef>

typedef __attribute__((ext_vector_type(4))) float f32x4;
typedef __attribute__((ext_vector_type(8))) short s16x8;
typedef __attribute__((ext_vector_type(4))) unsigned short u16x4;
typedef __attribute__((ext_vector_type(8))) unsigned short u16x8;

#define NB 32
#define DD 512
#define TT 4096
#define HH 512
#define TB 64     // t-tile per block
#define BK 32     // k per iteration
#define NKK 16    // 512/BK

__device__ __forceinline__ unsigned short f2bf(float f) {
  uint32_t u = __builtin_bit_cast(uint32_t, f);
  u += 0x7fffu + ((u >> 16) & 1u);   // RNE; inputs are normal floats
  return (unsigned short)(u >> 16);
}

__device__ __forceinline__ float tanh_fast(float x) {
  x = fminf(fmaxf(x, -15.f), 15.f);
  float e = __expf(2.f * x);
  return (e - 1.f) / (e + 1.f);
}

// --- A1: W1swz[kk][s][h] : 16B chunk = W1[h][kk*32 + s*8 .. +7] in bf16 ---
__global__ void kConvT(const float* __restrict__ w42, u16x8* __restrict__ W1swz) {
  int g = blockIdx.x * 256 + threadIdx.x;        // 0..32767 chunks
  int h = g & 511, sk = g >> 9;
  int kk = sk >> 2, s = sk & 3;
  const float* src = &w42[h * 1024 + kk * 32 + s * 8];
  f32x4 v0 = *reinterpret_cast<const f32x4*>(src);
  f32x4 v1 = *reinterpret_cast<const f32x4*>(src + 4);
  u16x8 c;
  c[0] = f2bf(v0.x); c[1] = f2bf(v0.y); c[2] = f2bf(v0.z); c[3] = f2bf(v0.w);
  c[4] = f2bf(v1.x); c[5] = f2bf(v1.y); c[6] = f2bf(v1.z); c[7] = f2bf(v1.w);
  W1swz[kk * 2048 + s * 512 + h] = c;
}

// --- A2: qterm[b,h] = w42[h,512:]·query[b] + b4[h] ---
__global__ void kQterm(const float* __restrict__ w42, const float* __restrict__ query,
                       const float* __restrict__ b4, float* __restrict__ qterm) {
  int wid = blockIdx.x * 4 + (threadIdx.x >> 6);
  int lane = threadIdx.x & 63;
  int b = wid >> 9, h = wid & 511;
  const float* wr = &w42[h * 1024 + 512];
  const float* q  = &query[b * 512];
  int d = lane * 8;
  f32x4 w0 = *(const f32x4*)&wr[d], w1 = *(const f32x4*)&wr[d + 4];
  f32x4 q0 = *(const f32x4*)&q[d],  q1 = *(const f32x4*)&q[d + 4];
  float s = w0.x*q0.x + w0.y*q0.y + w0.z*q0.z + w0.w*q0.w
          + w1.x*q1.x + w1.y*q1.y + w1.z*q1.z + w1.w*q1.w;
  #pragma unroll
  for (int off = 32; off; off >>= 1) s += __shfl_xor(s, off);
  if (lane == 0) qterm[b * 512 + h] = s + b4[h];
}

// --- B: fused GEMM + tanh + h-reduce + exp + values partial-output.
// Block: full H=512 x TB=64 t. 4 waves, wave tile 128h x 64t.
// P[b][tblk][v] = sum_{t in tile} values[b,v,t]*exp(n5[b,t]);  Zp = sum exp.
__global__ __launch_bounds__(256, 2) void kMain(
    const float* __restrict__ keys, const float* __restrict__ values,
    const u16x8* __restrict__ W1swz, const float* __restrict__ qterm,
    const float* __restrict__ w54, float* __restrict__ P, float* __restrict__ Zp) {
  __shared__ s16x8 Bs[2 * 4 * 64];   // 8 KB double-buffered B chunks
  __shared__ float red[4][64];
  __shared__ float e_s[64];

  int bid = blockIdx.x;
  int b = bid >> 6, tblk = bid & 63;
  int t0 = tblk * TB;
  int tid = threadIdx.x, lane = tid & 63, w = tid >> 6;
  int lr = lane & 15, lg = lane >> 4;

  const float* kp = keys + (size_t)b * DD * TT + (size_t)(w * 8) * TT + t0 + lane;
  const s16x8* ap = reinterpret_cast<const s16x8*>(W1swz) + lg * 512 + w * 128 + lr;

  f32x4 acc[8][4];
  #pragma unroll
  for (int m = 0; m < 8; ++m)
    #pragma unroll
    for (int n = 0; n < 4; ++n) acc[m][n] = (f32x4){0.f, 0.f, 0.f, 0.f};

  s16x8 af[2][8];
  float r[2][8];
  // prologue — af(0) issued FIRST so later B-waits never force it and vice versa
  #pragma unroll
  for (int m = 0; m < 8; ++m) af[0][m] = ap[m * 16];
  #pragma unroll
  for (int j = 0; j < 8; ++j) r[0][j] = kp[(size_t)j * TT];
  #pragma unroll
  for (int j = 0; j < 8; ++j) r[1][j] = kp[(size_t)(BK + j) * TT];

  #pragma unroll
  for (int kk = 0; kk < NKK; ++kk) {
    const int cur = kk & 1;
    // convert this step's B regs -> bf16 chunk -> LDS
    s16x8 c;
    #pragma unroll
    for (int j = 0; j < 8; ++j) c[j] = (short)f2bf(r[cur][j]);
    Bs[(cur * 4 + w) * 64 + lane] = c;

    // issue NEXT step's A-frags (L2) BEFORE the B prefetch: waiting on af(kk)
    // then never forces completion of a newer B set (in-order vmcnt).
    if (kk + 1 < NKK) {
      #pragma unroll
      for (int m = 0; m < 8; ++m) af[cur ^ 1][m] = ap[(kk + 1) * 2048 + m * 16];
    }
    // depth-2 B prefetch (HBM): issued 2 steps before consumption
    if (kk + 2 < NKK) {
      const float* kp2 = kp + (size_t)(kk + 2) * BK * TT;
      #pragma unroll
      for (int j = 0; j < 8; ++j) r[cur][j] = kp2[(size_t)j * TT];
    }

    asm volatile("s_waitcnt lgkmcnt(0)" ::: "memory");  // Bs writes visible
    __builtin_amdgcn_s_barrier();                        // vmcnt NOT drained

    s16x8 bf[4];
    #pragma unroll
    for (int n = 0; n < 4; ++n)
      bf[n] = Bs[(cur * 4 + lg) * 64 + n * 16 + lr];

    #pragma unroll
    for (int m = 0; m < 8; ++m)
      #pragma unroll
      for (int n = 0; n < 4; ++n)
        acc[m][n] = __builtin_amdgcn_mfma_f32_16x16x32_bf16(af[cur][m], bf[n], acc[m][n], 0, 0, 0);
  }

  // epilogue: tanh + w54-weighted reduce over this wave's 128 h
  float part[4] = {0.f, 0.f, 0.f, 0.f};
  int hb = w * 128;
  #pragma unroll
  for (int m = 0; m < 8; ++m) {
    #pragma unroll
    for (int rr = 0; rr < 4; ++rr) {
      int h = hb + m * 16 + lg * 4 + rr;     // C/D: row=(lane>>4)*4+reg
      float qv = qterm[b * HH + h];
      float wv = w54[h];
      #pragma unroll
      for (int n = 0; n < 4; ++n)
        part[n] += wv * tanh_fast(acc[m][n][rr] + qv);
    }
  }
  #pragma unroll
  for (int n = 0; n < 4; ++n) {
    part[n] += __shfl_xor(part[n], 16);
    part[n] += __shfl_xor(part[n], 32);
  }
  if (lane < 16) {
    #pragma unroll
    for (int n = 0; n < 4; ++n) red[w][n * 16 + lane] = part[n];
  }
  __syncthreads();
  if (tid < 64) {
    float v = red[0][tid] + red[1][tid] + red[2][tid] + red[3][tid];
    float e = __expf(v);                    // |n5| <~ 4: no max-sub needed
    e_s[tid] = e;
    float z = e;
    #pragma unroll
    for (int off = 32; off; off >>= 1) z += __shfl_xor(z, off);
    if (tid == 0) Zp[b * 64 + tblk] = z;
  }
  __syncthreads();

  // phase 2: partial output — wave w handles v rows [w*128, w*128+128)
  f32x4 ee = *(const f32x4*)&e_s[lr * 4];
  const float* vb = values + (size_t)b * DD * TT + t0 + lr * 4;
  float* Pb = P + ((size_t)b * 64 + tblk) * 512;
  int q = lane >> 4;
  #pragma unroll 8
  for (int it = 0; it < 32; ++it) {
    int v = w * 128 + it * 4 + q;
    f32x4 x = *(const f32x4*)&vb[(size_t)v * TT];
    float s = x.x * ee.x + x.y * ee.y + x.z * ee.z + x.w * ee.w;
    s += __shfl_xor(s, 1);
    s += __shfl_xor(s, 2);
    s += __shfl_xor(s, 4);
    s += __shfl_xor(s, 8);
    if (lr == 0) Pb[v] = s;
  }
}

// --- C: out[b,v] = (sum_tiles P[b,tile,v]) / (sum_tiles Zp[b,tile]) ---
__global__ void kFinal(const float* __restrict__ P, const float* __restrict__ Zp,
                       float* __restrict__ out) {
  int b = blockIdx.x, tid = threadIdx.x;
  __shared__ float zsh;
  if (tid < 64) {
    float z = Zp[b * 64 + tid];
    #pragma unroll
    for (int off = 32; off; off >>= 1) z += __shfl_xor(z, off);
    if (tid == 0) zsh = z;
  }
  __syncthreads();
  float inv = 1.f / zsh;
  float s0 = 0.f, s1 = 0.f;
  const float* Pb = P + (size_t)b * 64 * 512;
  for (int tile = 0; tile < 64; ++tile) {
    s0 += Pb[tile * 512 + tid];
    s1 += Pb[tile * 512 + 256 + tid];
  }
  out[b * 512 + tid] = s0 * inv;
  out[b * 512 + 256 + tid] = s1 * inv;
}

extern "C" void kernel_launch(void* const* d_in, const int* in_sizes, int n_in,
                              void* d_out, int out_size, void* d_ws, size_t ws_size,
                              hipStream_t stream) {
  const float* query  = (const float*)d_in[0];
  const float* keys   = (const float*)d_in[1];
  const float* values = (const float*)d_in[2];
  const float* w42    = (const float*)d_in[3];
  const float* b4     = (const float*)d_in[4];
  const float* w54    = (const float*)d_in[5];
  // d_in[6] (b5) shifts n5 by a constant -> softmax-invariant; unused.
  float* out = (float*)d_out;

  char* ws = (char*)d_ws;
  u16x8* W1swz = (u16x8*)ws;                       // 512 KB
  float* qterm = (float*)(ws + (512 << 10));       // 64 KB
  float* Zp    = (float*)(ws + (576 << 10));       // 8 KB   [B][64]
  float* P     = (float*)(ws + (1024 << 10));      // 4 MB   [B][64][512]

  kConvT <<<128, 256, 0, stream>>>(w42, W1swz);
  kQterm <<<4096, 256, 0, stream>>>(w42, query, b4, qterm);
  kMain  <<<2048, 256, 0, stream>>>(keys, values, W1swz, qterm, w54, P, Zp);
  kFinal <<<32, 256, 0, stream>>>(P, Zp, out);
}

// Round 4
// 172.445 us; speedup vs baseline: 1.2322x; 1.2322x over previous
//
#include <hip/hip_runtime.h>
#include <hip/hip_bf16.h>
#include <cstdint>
#include <cstddef>

typedef __attribute__((ext_vector_type(4))) float f32x4;
typedef __attribute__((ext_vector_type(8))) short s16x8;
typedef __attribute__((ext_vector_type(4))) unsigned short u16x4;
typedef __attribute__((ext_vector_type(8))) unsigned short u16x8;

#define NB 32
#define DD 512
#define TT 4096
#define HH 512
#define TB 64     // t-tile per block
#define BK 32     // k per iteration
#define NKK 16    // 512/BK

__device__ __forceinline__ unsigned short f2bf(float f) {
  uint32_t u = __builtin_bit_cast(uint32_t, f);
  u += 0x7fffu + ((u >> 16) & 1u);   // RNE
  return (unsigned short)(u >> 16);
}

__device__ __forceinline__ float tanh_fast(float x) {
  x = fminf(fmaxf(x, -15.f), 15.f);
  float e = __expf(2.f * x);
  return (e - 1.f) / (e + 1.f);
}

// --- A1: W1swz[kk][s][h] : 16B chunk = W1[h][kk*32 + s*8 .. +7] in bf16 ---
__global__ void kConvT(const float* __restrict__ w42, u16x8* __restrict__ W1swz) {
  int g = blockIdx.x * 256 + threadIdx.x;
  int h = g & 511, sk = g >> 9;
  int kk = sk >> 2, s = sk & 3;
  const float* src = &w42[h * 1024 + kk * 32 + s * 8];
  f32x4 v0 = *reinterpret_cast<const f32x4*>(src);
  f32x4 v1 = *reinterpret_cast<const f32x4*>(src + 4);
  u16x8 c;
  c[0] = f2bf(v0.x); c[1] = f2bf(v0.y); c[2] = f2bf(v0.z); c[3] = f2bf(v0.w);
  c[4] = f2bf(v1.x); c[5] = f2bf(v1.y); c[6] = f2bf(v1.z); c[7] = f2bf(v1.w);
  W1swz[kk * 2048 + s * 512 + h] = c;
}

// --- A2: qterm[b,h] = w42[h,512:]·query[b] + b4[h] ---
__global__ void kQterm(const float* __restrict__ w42, const float* __restrict__ query,
                       const float* __restrict__ b4, float* __restrict__ qterm) {
  int wid = blockIdx.x * 4 + (threadIdx.x >> 6);
  int lane = threadIdx.x & 63;
  int b = wid >> 9, h = wid & 511;
  const float* wr = &w42[h * 1024 + 512];
  const float* q  = &query[b * 512];
  int d = lane * 8;
  f32x4 w0 = *(const f32x4*)&wr[d], w1 = *(const f32x4*)&wr[d + 4];
  f32x4 q0 = *(const f32x4*)&q[d],  q1 = *(const f32x4*)&q[d + 4];
  float s = w0.x*q0.x + w0.y*q0.y + w0.z*q0.z + w0.w*q0.w
          + w1.x*q1.x + w1.y*q1.y + w1.z*q1.z + w1.w*q1.w;
  #pragma unroll
  for (int off = 32; off; off >>= 1) s += __shfl_xor(s, off);
  if (lane == 0) qterm[b * 512 + h] = s + b4[h];
}

// --- B: GEMM + tanh + h-reduce + exp.  e[b][t] = exp(n5[b][t]); Zp partials.
__global__ __launch_bounds__(256, 2) void kGemmE(
    const float* __restrict__ keys, const u16x8* __restrict__ W1swz,
    const float* __restrict__ qterm, const float* __restrict__ w54,
    float* __restrict__ e, float* __restrict__ Zp) {
  __shared__ s16x8 Bs[2 * 4 * 64];   // 8 KB double-buffered B chunks
  __shared__ float red[4][64];

  int bid = blockIdx.x;
  int b = bid >> 6, tblk = bid & 63;
  int t0 = tblk * TB;
  int tid = threadIdx.x, lane = tid & 63, w = tid >> 6;
  int lr = lane & 15, lg = lane >> 4;

  const float* kp = keys + (size_t)b * DD * TT + (size_t)(w * 8) * TT + t0 + lane;
  const s16x8* ap = reinterpret_cast<const s16x8*>(W1swz) + lg * 512 + w * 128 + lr;

  f32x4 acc[8][4];
  #pragma unroll
  for (int m = 0; m < 8; ++m)
    #pragma unroll
    for (int n = 0; n < 4; ++n) acc[m][n] = (f32x4){0.f, 0.f, 0.f, 0.f};

  s16x8 af[2][8];
  float r[2][8];
  // prologue: af(0) first, then B(0), B(1) — in-order vmcnt discipline
  #pragma unroll
  for (int m = 0; m < 8; ++m) af[0][m] = ap[m * 16];
  #pragma unroll
  for (int j = 0; j < 8; ++j) r[0][j] = kp[(size_t)j * TT];
  #pragma unroll
  for (int j = 0; j < 8; ++j) r[1][j] = kp[(size_t)(BK + j) * TT];

  #pragma unroll
  for (int kk = 0; kk < NKK; ++kk) {
    const int cur = kk & 1;
    s16x8 c;
    #pragma unroll
    for (int j = 0; j < 8; ++j) c[j] = (short)f2bf(r[cur][j]);
    Bs[(cur * 4 + w) * 64 + lane] = c;

    // next step's A-frags (L2) BEFORE the HBM prefetch: waiting on af never
    // forces a newer B set to complete (in-order vmcnt).
    if (kk + 1 < NKK) {
      #pragma unroll
      for (int m = 0; m < 8; ++m) af[cur ^ 1][m] = ap[(kk + 1) * 2048 + m * 16];
    }
    if (kk + 2 < NKK) {
      const float* kp2 = kp + (size_t)(kk + 2) * BK * TT;
      #pragma unroll
      for (int j = 0; j < 8; ++j) r[cur][j] = kp2[(size_t)j * TT];
    }

    asm volatile("s_waitcnt lgkmcnt(0)" ::: "memory");
    __builtin_amdgcn_s_barrier();

    s16x8 bf[4];
    #pragma unroll
    for (int n = 0; n < 4; ++n)
      bf[n] = Bs[(cur * 4 + lg) * 64 + n * 16 + lr];

    #pragma unroll
    for (int m = 0; m < 8; ++m)
      #pragma unroll
      for (int n = 0; n < 4; ++n)
        acc[m][n] = __builtin_amdgcn_mfma_f32_16x16x32_bf16(af[cur][m], bf[n], acc[m][n], 0, 0, 0);
  }

  // epilogue: tanh + w54-weighted reduce over this wave's 128 h
  float part[4] = {0.f, 0.f, 0.f, 0.f};
  int hb = w * 128;
  #pragma unroll
  for (int m = 0; m < 8; ++m) {
    #pragma unroll
    for (int rr = 0; rr < 4; ++rr) {
      int h = hb + m * 16 + lg * 4 + rr;     // C/D: row=(lane>>4)*4+reg
      float qv = qterm[b * HH + h];
      float wv = w54[h];
      #pragma unroll
      for (int n = 0; n < 4; ++n)
        part[n] += wv * tanh_fast(acc[m][n][rr] + qv);
    }
  }
  #pragma unroll
  for (int n = 0; n < 4; ++n) {
    part[n] += __shfl_xor(part[n], 16);
    part[n] += __shfl_xor(part[n], 32);
  }
  if (lane < 16) {
    #pragma unroll
    for (int n = 0; n < 4; ++n) red[w][n * 16 + lane] = part[n];
  }
  __syncthreads();
  if (tid < 64) {
    float v = red[0][tid] + red[1][tid] + red[2][tid] + red[3][tid];
    float ev = __expf(v);                    // |n5| <~ 4: no max-sub needed
    e[b * TT + t0 + tid] = ev;
    float z = ev;
    #pragma unroll
    for (int off = 32; off; off >>= 1) z += __shfl_xor(z, off);
    if (tid == 0) Zp[b * 64 + tblk] = z;
  }
}

// --- C: Zinv[b] = 1 / sum_tiles Zp[b][tile] ---
__global__ void kZinv(const float* __restrict__ Zp, float* __restrict__ Zinv) {
  int b = blockIdx.x, lane = threadIdx.x;
  float z = Zp[b * 64 + lane];
  #pragma unroll
  for (int off = 32; off; off >>= 1) z += __shfl_xor(z, off);
  if (lane == 0) Zinv[b] = 1.f / z;
}

// --- D: out[b,v] = Zinv[b] * values[b,v,:]·e[b,:]  (one wave per row) ---
__global__ void kOut(const float* __restrict__ values, const float* __restrict__ e,
                     const float* __restrict__ Zinv, float* __restrict__ out) {
  int blk = blockIdx.x;
  int b = blk >> 7;
  int wid = threadIdx.x >> 6, lane = threadIdx.x & 63;
  int v = (blk & 127) * 4 + wid;
  const float* row = &values[((size_t)b * 512 + v) * TT];
  const float* wv = &e[b * TT];
  float s = 0.f;
  #pragma unroll
  for (int i = 0; i < 16; ++i) {
    int t = (i * 64 + lane) * 4;
    f32x4 x = *(const f32x4*)&row[t];
    f32x4 y = *(const f32x4*)&wv[t];
    s += x.x * y.x + x.y * y.y + x.z * y.z + x.w * y.w;
  }
  #pragma unroll
  for (int off = 32; off; off >>= 1) s += __shfl_xor(s, off);
  if (lane == 0) out[b * 512 + v] = s * Zinv[b];
}

extern "C" void kernel_launch(void* const* d_in, const int* in_sizes, int n_in,
                              void* d_out, int out_size, void* d_ws, size_t ws_size,
                              hipStream_t stream) {
  const float* query  = (const float*)d_in[0];
  const float* keys   = (const float*)d_in[1];
  const float* values = (const float*)d_in[2];
  const float* w42    = (const float*)d_in[3];
  const float* b4     = (const float*)d_in[4];
  const float* w54    = (const float*)d_in[5];
  // d_in[6] (b5) shifts n5 by a constant -> softmax-invariant; unused.
  float* out = (float*)d_out;

  char* ws = (char*)d_ws;
  u16x8* W1swz = (u16x8*)ws;                       // 512 KB
  float* qterm = (float*)(ws + (512 << 10));       // 64 KB
  float* Zp    = (float*)(ws + (576 << 10));       // 8 KB   [B][64]
  float* Zinv  = (float*)(ws + (592 << 10));       // 128 B
  float* e     = (float*)(ws + (640 << 10));       // 512 KB [B][T]

  kConvT <<<128, 256, 0, stream>>>(w42, W1swz);
  kQterm <<<4096, 256, 0, stream>>>(w42, query, b4, qterm);
  kGemmE <<<2048, 256, 0, stream>>>(keys, W1swz, qterm, w54, e, Zp);
  kZinv  <<<32, 64, 0, stream>>>(Zp, Zinv);
  kOut   <<<4096, 256, 0, stream>>>(values, e, Zinv, out);
}